// Round 1
// baseline (3402.957 us; speedup 1.0000x reference)
//
#include <hip/hip_runtime.h>

#define NNODES 100000
#define NEDGES 640000
#define HEADS 4
#define DHEAD 32
#define OUTF 128
#define ECOLS 118
#define ATT_SCALE 0.17677669529663687f  // 1/sqrt(32)

// ---------- helpers ----------
__device__ __forceinline__ unsigned fkey(float f) {
    unsigned b = __float_as_uint(f);
    return (b & 0x80000000u) ? ~b : (b | 0x80000000u);
}
__device__ __forceinline__ float fdecode(unsigned k) {
    unsigned b = (k & 0x80000000u) ? (k ^ 0x80000000u) : ~k;
    return __uint_as_float(b);
}
__device__ __forceinline__ unsigned short f2bf(float f) {
    unsigned u = __float_as_uint(f);
    u += 0x7FFFu + ((u >> 16) & 1u);   // RNE
    return (unsigned short)(u >> 16);
}
__device__ __forceinline__ float bf2f(unsigned short h) {
    return __uint_as_float(((unsigned)h) << 16);
}

// ---------- prep: build wmod (118x128) and T (4x128) for both layers ----------
__global__ void prep_kernel(const float* __restrict__ we1, const float* __restrict__ we2,
                            const float* __restrict__ emb,
                            float* __restrict__ wmod1, float* __restrict__ wmod2,
                            float* __restrict__ T1, float* __restrict__ T2) {
    int idx = blockIdx.x * blockDim.x + threadIdx.x;
    int stride = gridDim.x * blockDim.x;
    for (int i = idx; i < ECOLS * OUTF; i += stride) {
        int j = i / OUTF, c = i % OUTF;
        float v1, v2;
        if (j < 3)      { v1 = we1[j * OUTF + c];       v2 = we2[j * OUTF + c]; }
        else if (j == 3){ v1 = 0.f;                      v2 = 0.f; }
        else            { v1 = we1[(j - 1) * OUTF + c]; v2 = we2[(j - 1) * OUTF + c]; }
        wmod1[i] = v1; wmod2[i] = v2;
    }
    for (int i = idx; i < 4 * OUTF; i += stride) {
        int t = i / OUTF, c = i % OUTF;
        float a1 = 0.f, a2 = 0.f;
        #pragma unroll
        for (int r = 0; r < 8; r++) {
            float ev = emb[t * 8 + r];
            a1 += ev * we1[(117 + r) * OUTF + c];
            a2 += ev * we2[(117 + r) * OUTF + c];
        }
        T1[i] = a1; T2[i] = a2;
    }
}

// ---------- node GEMM: Y = act(X) @ W + bias ; X (n x Kdim), W (Kdim x 128) ----------
__global__ __launch_bounds__(256) void node_gemm(const float* __restrict__ X,
                                                 const float* __restrict__ W,
                                                 const float* __restrict__ Bias,
                                                 float* __restrict__ Y,
                                                 int n, int Kdim, int relu_x) {
    __shared__ float As[64][17];
    __shared__ float Bs[16][OUTF];
    int tid = threadIdx.x;
    int tx = tid & 15, ty = tid >> 4;
    int rowbase = blockIdx.x * 64;
    int c0 = tx * 8, r0 = ty * 4;
    float acc[4][8];
    #pragma unroll
    for (int i = 0; i < 4; i++)
        #pragma unroll
        for (int j = 0; j < 8; j++) acc[i][j] = 0.f;

    for (int k0 = 0; k0 < Kdim; k0 += 16) {
        #pragma unroll
        for (int t = 0; t < 4; t++) {
            int idx = tid * 4 + t;
            int r = idx >> 4, kk = idx & 15;
            int gr = rowbase + r, gk = k0 + kk;
            float v = 0.f;
            if (gr < n && gk < Kdim) v = X[(size_t)gr * Kdim + gk];
            if (relu_x) v = fmaxf(v, 0.f);
            As[r][kk] = v;
        }
        #pragma unroll
        for (int t = 0; t < 8; t++) {
            int idx = tid + t * 256;
            int kk = idx >> 7, c = idx & 127;
            int gk = k0 + kk;
            Bs[kk][c] = (gk < Kdim) ? W[(size_t)gk * OUTF + c] : 0.f;
        }
        __syncthreads();
        #pragma unroll
        for (int kk = 0; kk < 16; kk++) {
            float a0 = As[r0 + 0][kk], a1 = As[r0 + 1][kk];
            float a2 = As[r0 + 2][kk], a3 = As[r0 + 3][kk];
            float4 blo = *(const float4*)&Bs[kk][c0];
            float4 bhi = *(const float4*)&Bs[kk][c0 + 4];
            float b[8] = {blo.x, blo.y, blo.z, blo.w, bhi.x, bhi.y, bhi.z, bhi.w};
            #pragma unroll
            for (int j = 0; j < 8; j++) {
                acc[0][j] += a0 * b[j];
                acc[1][j] += a1 * b[j];
                acc[2][j] += a2 * b[j];
                acc[3][j] += a3 * b[j];
            }
        }
        __syncthreads();
    }
    #pragma unroll
    for (int i = 0; i < 4; i++) {
        int gr = rowbase + r0 + i;
        if (gr < n) {
            float4 olo, ohi;
            olo.x = acc[i][0] + Bias[c0 + 0]; olo.y = acc[i][1] + Bias[c0 + 1];
            olo.z = acc[i][2] + Bias[c0 + 2]; olo.w = acc[i][3] + Bias[c0 + 3];
            ohi.x = acc[i][4] + Bias[c0 + 4]; ohi.y = acc[i][5] + Bias[c0 + 5];
            ohi.z = acc[i][6] + Bias[c0 + 6]; ohi.w = acc[i][7] + Bias[c0 + 7];
            *(float4*)&Y[(size_t)gr * OUTF + c0] = olo;
            *(float4*)&Y[(size_t)gr * OUTF + c0 + 4] = ohi;
        }
    }
}

// ---------- edge alpha pass: ee = ea@wmod + T[etype]; store ee (bf16), alpha; atomicMax m ----------
__global__ __launch_bounds__(256) void edge_alpha(const float* __restrict__ EA,
                                                  const int* __restrict__ srcI,
                                                  const int* __restrict__ dstI,
                                                  const float* __restrict__ Wmod,
                                                  const float* __restrict__ Tt,
                                                  const float* __restrict__ Qm,
                                                  const float* __restrict__ Km,
                                                  unsigned short* __restrict__ EE,
                                                  float* __restrict__ alpha,
                                                  unsigned* __restrict__ mkeys,
                                                  int E) {
    __shared__ float As[64][17];
    __shared__ float Bs[16][OUTF];
    int tid = threadIdx.x;
    int tx = tid & 15, ty = tid >> 4;
    int e0 = blockIdx.x * 64;
    int c0 = tx * 8, r0 = ty * 4;
    float acc[4][8];
    #pragma unroll
    for (int i = 0; i < 4; i++)
        #pragma unroll
        for (int j = 0; j < 8; j++) acc[i][j] = 0.f;

    for (int k0 = 0; k0 < ECOLS; k0 += 16) {
        #pragma unroll
        for (int t = 0; t < 4; t++) {
            int idx = tid * 4 + t;
            int r = idx >> 4, kk = idx & 15;
            int gk = k0 + kk;
            int ge = e0 + r;
            float v = 0.f;
            if (ge < E && gk < ECOLS) v = EA[(size_t)ge * ECOLS + gk];
            As[r][kk] = v;
        }
        #pragma unroll
        for (int t = 0; t < 8; t++) {
            int idx = tid + t * 256;
            int kk = idx >> 7, c = idx & 127;
            int gk = k0 + kk;
            Bs[kk][c] = (gk < ECOLS) ? Wmod[(size_t)gk * OUTF + c] : 0.f;
        }
        __syncthreads();
        #pragma unroll
        for (int kk = 0; kk < 16; kk++) {
            float a0 = As[r0 + 0][kk], a1 = As[r0 + 1][kk];
            float a2 = As[r0 + 2][kk], a3 = As[r0 + 3][kk];
            float4 blo = *(const float4*)&Bs[kk][c0];
            float4 bhi = *(const float4*)&Bs[kk][c0 + 4];
            float b[8] = {blo.x, blo.y, blo.z, blo.w, bhi.x, bhi.y, bhi.z, bhi.w};
            #pragma unroll
            for (int j = 0; j < 8; j++) {
                acc[0][j] += a0 * b[j];
                acc[1][j] += a1 * b[j];
                acc[2][j] += a2 * b[j];
                acc[3][j] += a3 * b[j];
            }
        }
        __syncthreads();
    }

    #pragma unroll
    for (int i = 0; i < 4; i++) {
        int e = e0 + r0 + i;
        if (e < E) {
            int d = dstI[e], s = srcI[e];
            int et = (int)EA[(size_t)e * ECOLS + 3];
            const float4* tq = (const float4*)(Tt + et * OUTF + c0);
            float4 tlo = tq[0], thi = tq[1];
            float tt[8] = {tlo.x, tlo.y, tlo.z, tlo.w, thi.x, thi.y, thi.z, thi.w};
            const float4* q4 = (const float4*)(Qm + (size_t)d * OUTF + c0);
            float4 qlo = q4[0], qhi = q4[1];
            float qv[8] = {qlo.x, qlo.y, qlo.z, qlo.w, qhi.x, qhi.y, qhi.z, qhi.w};
            const float4* k4 = (const float4*)(Km + (size_t)s * OUTF + c0);
            float4 klo = k4[0], khi = k4[1];
            float kv[8] = {klo.x, klo.y, klo.z, klo.w, khi.x, khi.y, khi.z, khi.w};

            float ee[8];
            float part = 0.f;
            #pragma unroll
            for (int j = 0; j < 8; j++) {
                ee[j] = acc[i][j] + tt[j];
                part += qv[j] * (kv[j] + ee[j]);
            }
            // pack+store ee as bf16 (8 vals = 16B)
            uint4 pk;
            pk.x = (unsigned)f2bf(ee[0]) | ((unsigned)f2bf(ee[1]) << 16);
            pk.y = (unsigned)f2bf(ee[2]) | ((unsigned)f2bf(ee[3]) << 16);
            pk.z = (unsigned)f2bf(ee[4]) | ((unsigned)f2bf(ee[5]) << 16);
            pk.w = (unsigned)f2bf(ee[6]) | ((unsigned)f2bf(ee[7]) << 16);
            *(uint4*)(EE + (size_t)e * OUTF + c0) = pk;

            // reduce 8-col partial across the 4 lanes of this head (lane bits 0..1)
            part += __shfl_xor(part, 1);
            part += __shfl_xor(part, 2);
            if ((tx & 3) == 0) {
                int h = tx >> 2;
                float al = part * ATT_SCALE;
                alpha[(size_t)e * 4 + h] = al;
                atomicMax(&mkeys[(size_t)d * 4 + h], fkey(al));
            }
        }
    }
}

// ---------- exp pass: p = exp(alpha - m[dst]); atomicAdd s ----------
__global__ void exp_pass(float* __restrict__ alpha,
                         const int* __restrict__ dstI,
                         const unsigned* __restrict__ mkeys,
                         float* __restrict__ ssum, int E) {
    int idx = blockIdx.x * blockDim.x + threadIdx.x;
    int total = E * 4;
    int stride = gridDim.x * blockDim.x;
    for (; idx < total; idx += stride) {
        int e = idx >> 2, h = idx & 3;
        int d = dstI[e];
        float m = fdecode(mkeys[(size_t)d * 4 + h]);
        float p = __expf(alpha[idx] - m);
        alpha[idx] = p;
        atomicAdd(&ssum[(size_t)d * 4 + h], p);
    }
}

// ---------- message pass: out[dst] += (v[src] + ee) * p/(s+eps) ; 1 wave per edge ----------
__global__ __launch_bounds__(256) void edge_msg(const unsigned short* __restrict__ EE,
                                                const int* __restrict__ srcI,
                                                const int* __restrict__ dstI,
                                                const float* __restrict__ Vm,
                                                const float* __restrict__ P,
                                                const float* __restrict__ ssum,
                                                float* __restrict__ Out, int E) {
    int gw = (int)((blockIdx.x * (size_t)blockDim.x + threadIdx.x) >> 6);
    int lane = threadIdx.x & 63;
    if (gw >= E) return;
    int e = gw;
    int d = dstI[e], s = srcI[e];
    int c = lane * 2;
    int h = c >> 5;
    float p = P[(size_t)e * 4 + h];
    float a = p / (ssum[(size_t)d * 4 + h] + 1e-16f);
    unsigned eeb = *(const unsigned*)(EE + (size_t)e * OUTF + c);
    float2 vv = *(const float2*)(Vm + (size_t)s * OUTF + c);
    float m0 = (vv.x + bf2f((unsigned short)(eeb & 0xFFFFu))) * a;
    float m1 = (vv.y + bf2f((unsigned short)(eeb >> 16))) * a;
    atomicAdd(&Out[(size_t)d * OUTF + c], m0);
    atomicAdd(&Out[(size_t)d * OUTF + c + 1], m1);
}

extern "C" void kernel_launch(void* const* d_in, const int* in_sizes, int n_in,
                              void* d_out, int out_size, void* d_ws, size_t ws_size,
                              hipStream_t stream) {
    const float* x    = (const float*)d_in[0];
    const int*   ei   = (const int*)d_in[1];
    const float* ea   = (const float*)d_in[2];
    const float* emb  = (const float*)d_in[3];
    const float* w1q  = (const float*)d_in[4];  const float* b1q = (const float*)d_in[5];
    const float* w1k  = (const float*)d_in[6];  const float* b1k = (const float*)d_in[7];
    const float* w1v  = (const float*)d_in[8];  const float* b1v = (const float*)d_in[9];
    const float* w1e  = (const float*)d_in[10];
    const float* w1s  = (const float*)d_in[11]; const float* b1s = (const float*)d_in[12];
    const float* w2q  = (const float*)d_in[13]; const float* b2q = (const float*)d_in[14];
    const float* w2k  = (const float*)d_in[15]; const float* b2k = (const float*)d_in[16];
    const float* w2v  = (const float*)d_in[17]; const float* b2v = (const float*)d_in[18];
    const float* w2e  = (const float*)d_in[19];
    const float* w2s  = (const float*)d_in[20]; const float* b2s = (const float*)d_in[21];

    const int N = NNODES, E = NEDGES;
    const int* srcI = ei;
    const int* dstI = ei + E;

    float* ws = (float*)d_ws;
    size_t NF = (size_t)N * OUTF;
    float* Q     = ws;
    float* Kf    = Q  + NF;
    float* Vf    = Kf + NF;
    float* Hb    = Vf + NF;
    float* alpha = Hb + NF;
    unsigned* mkeys = (unsigned*)(alpha + (size_t)E * 4);
    float* ssum  = (float*)(mkeys + (size_t)N * 4);
    float* wmod1 = ssum + (size_t)N * 4;
    float* wmod2 = wmod1 + ECOLS * OUTF;
    float* T1    = wmod2 + ECOLS * OUTF;
    float* T2    = T1 + 4 * OUTF;
    unsigned short* EE = (unsigned short*)(T2 + 4 * OUTF);

    prep_kernel<<<64, 256, 0, stream>>>(w1e, w2e, emb, wmod1, wmod2, T1, T2);

    int ngrid = (N + 63) / 64;
    int egrid = (E + 63) / 64;

    // ---- layer 1 ----
    node_gemm<<<ngrid, 256, 0, stream>>>(x, w1q, b1q, Q,  N, 100, 0);
    node_gemm<<<ngrid, 256, 0, stream>>>(x, w1k, b1k, Kf, N, 100, 0);
    node_gemm<<<ngrid, 256, 0, stream>>>(x, w1v, b1v, Vf, N, 100, 0);
    node_gemm<<<ngrid, 256, 0, stream>>>(x, w1s, b1s, Hb, N, 100, 0);
    hipMemsetAsync(mkeys, 0, (size_t)N * 4 * sizeof(unsigned) * 2, stream);
    edge_alpha<<<egrid, 256, 0, stream>>>(ea, srcI, dstI, wmod1, T1, Q, Kf, EE, alpha, mkeys, E);
    exp_pass<<<4096, 256, 0, stream>>>(alpha, dstI, mkeys, ssum, E);
    edge_msg<<<(E + 3) / 4, 256, 0, stream>>>(EE, srcI, dstI, Vf, alpha, ssum, Hb, E);

    // ---- layer 2 (relu applied on X load) ----
    node_gemm<<<ngrid, 256, 0, stream>>>(Hb, w2q, b2q, Q,  N, 128, 1);
    node_gemm<<<ngrid, 256, 0, stream>>>(Hb, w2k, b2k, Kf, N, 128, 1);
    node_gemm<<<ngrid, 256, 0, stream>>>(Hb, w2v, b2v, Vf, N, 128, 1);
    node_gemm<<<ngrid, 256, 0, stream>>>(Hb, w2s, b2s, (float*)d_out, N, 128, 1);
    hipMemsetAsync(mkeys, 0, (size_t)N * 4 * sizeof(unsigned) * 2, stream);
    edge_alpha<<<egrid, 256, 0, stream>>>(ea, srcI, dstI, wmod2, T2, Q, Kf, EE, alpha, mkeys, E);
    exp_pass<<<4096, 256, 0, stream>>>(alpha, dstI, mkeys, ssum, E);
    edge_msg<<<(E + 3) / 4, 256, 0, stream>>>(EE, srcI, dstI, Vf, alpha, ssum, (float*)d_out, E);
}

// Round 2
// 2650.053 us; speedup vs baseline: 1.2841x; 1.2841x over previous
//
#include <hip/hip_runtime.h>

#define NN 100000
#define NE 640000
#define OUTF 128
#define K1 100
#define KE 118
#define KPAD 128
#define ASTR 136              // LDS row stride (ushorts): 272B = 16B-mult, 2-way banks only
#define ATT_SCALE 0.17677669529663687f

typedef __attribute__((ext_vector_type(8))) short short8;
typedef __attribute__((ext_vector_type(4))) float f32x4;

__device__ __forceinline__ unsigned fkey(float f) {
    unsigned b = __float_as_uint(f);
    return (b & 0x80000000u) ? ~b : (b | 0x80000000u);
}
__device__ __forceinline__ float fdecode(unsigned k) {
    unsigned b = (k & 0x80000000u) ? (k ^ 0x80000000u) : ~k;
    return __uint_as_float(b);
}
__device__ __forceinline__ unsigned short f2bf(float f) {
    unsigned u = __float_as_uint(f);
    u += 0x7FFFu + ((u >> 16) & 1u);   // RNE
    return (unsigned short)(u >> 16);
}
__device__ __forceinline__ float bf2f(unsigned short h) {
    return __uint_as_float(((unsigned)h) << 16);
}

// ---------- prep: transposed bf16 weights, T tables, fused biases ----------
__global__ void prep_kernel(
    const float* __restrict__ w1q, const float* __restrict__ w1k,
    const float* __restrict__ w1v, const float* __restrict__ w1s,
    const float* __restrict__ w2q, const float* __restrict__ w2k,
    const float* __restrict__ w2v, const float* __restrict__ w2s,
    const float* __restrict__ we1, const float* __restrict__ we2,
    const float* __restrict__ emb,
    const float* __restrict__ b1q, const float* __restrict__ b1k,
    const float* __restrict__ b1v, const float* __restrict__ b1s,
    const float* __restrict__ b2q, const float* __restrict__ b2k,
    const float* __restrict__ b2v, const float* __restrict__ b2s,
    unsigned short* __restrict__ WT1, unsigned short* __restrict__ WT2,
    unsigned short* __restrict__ WmT1, unsigned short* __restrict__ WmT2,
    float* __restrict__ T1, float* __restrict__ T2,
    float* __restrict__ bias1, float* __restrict__ bias2)
{
    int idx = blockIdx.x * blockDim.x + threadIdx.x;
    int stride = gridDim.x * blockDim.x;
    // WT: [512 cols][128 k], bf16. col block 0..3 = q,k,v,s
    for (int i = idx; i < 512 * KPAD; i += stride) {
        int col = i >> 7, k = i & 127;
        int which = col >> 7, c = col & 127;
        const float* s1 = (which == 0) ? w1q : (which == 1) ? w1k : (which == 2) ? w1v : w1s;
        const float* s2 = (which == 0) ? w2q : (which == 1) ? w2k : (which == 2) ? w2v : w2s;
        float v1 = (k < K1) ? s1[k * OUTF + c] : 0.f;
        float v2 = s2[k * OUTF + c];                       // layer-2 K = 128
        WT1[i] = f2bf(v1); WT2[i] = f2bf(v2);
    }
    // WmT: [128 cols][128 k]; k==3 zeroed (etype folded into T), k in [4,118) -> we row k-1
    for (int i = idx; i < OUTF * KPAD; i += stride) {
        int col = i >> 7, k = i & 127;
        float v1 = 0.f, v2 = 0.f;
        if (k < 3)                 { v1 = we1[k * OUTF + col];       v2 = we2[k * OUTF + col]; }
        else if (k >= 4 && k < KE) { v1 = we1[(k - 1) * OUTF + col]; v2 = we2[(k - 1) * OUTF + col]; }
        WmT1[i] = f2bf(v1); WmT2[i] = f2bf(v2);
    }
    // T[etype][col] = emb[etype] @ we rows 117..124
    for (int i = idx; i < 4 * OUTF; i += stride) {
        int t = i >> 7, c = i & 127;
        float a1 = 0.f, a2 = 0.f;
        #pragma unroll
        for (int r = 0; r < 8; r++) {
            float ev = emb[t * 8 + r];
            a1 += ev * we1[(117 + r) * OUTF + c];
            a2 += ev * we2[(117 + r) * OUTF + c];
        }
        T1[i] = a1; T2[i] = a2;
    }
    for (int i = idx; i < 512; i += stride) {
        int which = i >> 7, c = i & 127;
        const float* sb1 = (which == 0) ? b1q : (which == 1) ? b1k : (which == 2) ? b1v : b1s;
        const float* sb2 = (which == 0) ? b2q : (which == 1) ? b2k : (which == 2) ? b2v : b2s;
        bias1[i] = sb1[c]; bias2[i] = sb2[c];
    }
}

// ---------- fused node GEMM (MFMA): Y[.,512] = act(X) @ Wcat + biascat ----------
// 4 waves 2x2, wave tile 64x64, loop nb over 4 col-blocks (B frags direct from global)
__global__ __launch_bounds__(256) void node_mfma(
    const float* __restrict__ X, int ldx, int Kdim, int relu, int n,
    const unsigned short* __restrict__ WT, const float* __restrict__ bias,
    float* __restrict__ Y0, float* __restrict__ Y1,
    float* __restrict__ Y2, float* __restrict__ Y3,
    int ld012, int ld3)
{
    __shared__ unsigned short Alds[128][ASTR];
    int tid = threadIdx.x;
    int rowbase = blockIdx.x * 128;

    for (int idx = tid; idx < 128 * 68; idx += 256) {
        int r = idx / 68, kv = idx % 68;
        int k = kv * 2;
        float2 v = make_float2(0.f, 0.f);
        int gr = rowbase + r;
        if (gr < n && k < Kdim) v = *(const float2*)(X + (size_t)gr * ldx + k);
        if (relu) { v.x = fmaxf(v.x, 0.f); v.y = fmaxf(v.y, 0.f); }
        unsigned pv = (unsigned)f2bf(v.x) | ((unsigned)f2bf(v.y) << 16);
        *(unsigned*)&Alds[r][k] = pv;
    }
    __syncthreads();

    int lane = tid & 63, wid = tid >> 6;
    int wm = wid >> 1, wn = wid & 1;
    int l15 = lane & 15, l4 = lane >> 4;

    for (int nb = 0; nb < 4; nb++) {
        f32x4 acc[4][4];
        #pragma unroll
        for (int mf = 0; mf < 4; mf++)
            #pragma unroll
            for (int nf = 0; nf < 4; nf++)
                acc[mf][nf] = (f32x4){0.f, 0.f, 0.f, 0.f};

        const unsigned short* wbase = WT + (size_t)(nb * 128 + wn * 64 + l15) * KPAD + l4 * 8;
        #pragma unroll
        for (int ks = 0; ks < 4; ks++) {
            short8 af[4], bfr[4];
            #pragma unroll
            for (int mf = 0; mf < 4; mf++)
                af[mf] = *(const short8*)&Alds[wm * 64 + mf * 16 + l15][ks * 32 + l4 * 8];
            #pragma unroll
            for (int nf = 0; nf < 4; nf++)
                bfr[nf] = *(const short8*)(wbase + (size_t)nf * 16 * KPAD + ks * 32);
            #pragma unroll
            for (int mf = 0; mf < 4; mf++)
                #pragma unroll
                for (int nf = 0; nf < 4; nf++)
                    acc[mf][nf] = __builtin_amdgcn_mfma_f32_16x16x32_bf16(af[mf], bfr[nf], acc[mf][nf], 0, 0, 0);
        }

        float* Yb = (nb == 0) ? Y0 : (nb == 1) ? Y1 : (nb == 2) ? Y2 : Y3;
        int ld = (nb == 3) ? ld3 : ld012;
        #pragma unroll
        for (int nf = 0; nf < 4; nf++) {
            int col = wn * 64 + nf * 16 + l15;
            float bv = bias[nb * 128 + col];
            #pragma unroll
            for (int mf = 0; mf < 4; mf++) {
                #pragma unroll
                for (int rr = 0; rr < 4; rr++) {
                    int row = rowbase + wm * 64 + mf * 16 + l4 * 4 + rr;
                    if (row < n) Yb[(size_t)row * ld + col] = acc[mf][nf][rr] + bv;
                }
            }
        }
    }
}

// ---------- edge GEMM (MFMA) + alpha epilogue ----------
__global__ __launch_bounds__(256) void edge_mfma(
    const float* __restrict__ EA,
    const int* __restrict__ srcI, const int* __restrict__ dstI,
    const unsigned short* __restrict__ WmT, const float* __restrict__ Tt,
    const float* __restrict__ Qm, const float* __restrict__ Km, int ldqk,
    unsigned short* __restrict__ EE, float* __restrict__ alphaOut,
    unsigned* __restrict__ mkeys)
{
    __shared__ unsigned short Alds[128][ASTR];
    __shared__ int et_lds[128];
    __shared__ float Tlds[4 * OUTF];
    int tid = threadIdx.x;
    int e0 = blockIdx.x * 128;   // NE % 128 == 0

    for (int idx = tid; idx < 128 * 68; idx += 256) {
        int r = idx / 68, kv = idx % 68;
        int k = kv * 2;
        float2 v = make_float2(0.f, 0.f);
        if (k < KE) v = *(const float2*)(EA + (size_t)(e0 + r) * KE + k);
        unsigned pv = (unsigned)f2bf(v.x) | ((unsigned)f2bf(v.y) << 16);
        *(unsigned*)&Alds[r][k] = pv;
    }
    if (tid < 128) et_lds[tid] = (int)EA[(size_t)(e0 + tid) * KE + 3];
    for (int i = tid; i < 4 * OUTF; i += 256) Tlds[i] = Tt[i];
    __syncthreads();

    int lane = tid & 63, wid = tid >> 6;
    int wm = wid >> 1, wn = wid & 1;
    int l15 = lane & 15, l4 = lane >> 4;

    f32x4 acc[4][4];
    #pragma unroll
    for (int mf = 0; mf < 4; mf++)
        #pragma unroll
        for (int nf = 0; nf < 4; nf++)
            acc[mf][nf] = (f32x4){0.f, 0.f, 0.f, 0.f};

    const unsigned short* wbase = WmT + (size_t)(wn * 64 + l15) * KPAD + l4 * 8;
    #pragma unroll
    for (int ks = 0; ks < 4; ks++) {
        short8 af[4], bfr[4];
        #pragma unroll
        for (int mf = 0; mf < 4; mf++)
            af[mf] = *(const short8*)&Alds[wm * 64 + mf * 16 + l15][ks * 32 + l4 * 8];
        #pragma unroll
        for (int nf = 0; nf < 4; nf++)
            bfr[nf] = *(const short8*)(wbase + (size_t)nf * 16 * KPAD + ks * 32);
        #pragma unroll
        for (int mf = 0; mf < 4; mf++)
            #pragma unroll
            for (int nf = 0; nf < 4; nf++)
                acc[mf][nf] = __builtin_amdgcn_mfma_f32_16x16x32_bf16(af[mf], bfr[nf], acc[mf][nf], 0, 0, 0);
    }
    __syncthreads();   // everyone done reading A tile

    // write ee = acc + T[etype] back into the A tile as bf16
    #pragma unroll
    for (int mf = 0; mf < 4; mf++) {
        #pragma unroll
        for (int rr = 0; rr < 4; rr++) {
            int row = wm * 64 + mf * 16 + l4 * 4 + rr;
            int et = et_lds[row];
            #pragma unroll
            for (int nf = 0; nf < 4; nf++) {
                int col = wn * 64 + nf * 16 + l15;
                Alds[row][col] = f2bf(acc[mf][nf][rr] + Tlds[et * OUTF + col]);
            }
        }
    }
    __syncthreads();

    // coalesced EE store (uint4 = 8 bf16)
    size_t ebase = (size_t)e0 * OUTF;
    for (int i = tid; i < 2048; i += 256) {
        int row = i >> 4, col = (i & 15) << 3;
        uint4 v = *(const uint4*)&Alds[row][col];
        *(uint4*)(EE + ebase + (size_t)row * OUTF + col) = v;
    }

    // alpha: 2 threads per edge, 64 cols (= 2 heads) each, no cross-lane reduce
    int r = tid >> 1, hf = tid & 1;
    int e = e0 + r;
    int d = dstI[e], s = srcI[e];
    const float* q = Qm + (size_t)d * ldqk + hf * 64;
    const float* kk = Km + (size_t)s * ldqk + hf * 64;
    float acch[2] = {0.f, 0.f};
    #pragma unroll
    for (int p = 0; p < 2; p++) {
        #pragma unroll
        for (int jv = 0; jv < 4; jv++) {
            int c = p * 32 + jv * 8;
            float4 q0 = *(const float4*)(q + c);
            float4 q1 = *(const float4*)(q + c + 4);
            float4 k0 = *(const float4*)(kk + c);
            float4 k1 = *(const float4*)(kk + c + 4);
            short8 ev = *(const short8*)&Alds[r][hf * 64 + c];
            acch[p] += q0.x * (k0.x + bf2f((unsigned short)ev[0]))
                     + q0.y * (k0.y + bf2f((unsigned short)ev[1]))
                     + q0.z * (k0.z + bf2f((unsigned short)ev[2]))
                     + q0.w * (k0.w + bf2f((unsigned short)ev[3]))
                     + q1.x * (k1.x + bf2f((unsigned short)ev[4]))
                     + q1.y * (k1.y + bf2f((unsigned short)ev[5]))
                     + q1.z * (k1.z + bf2f((unsigned short)ev[6]))
                     + q1.w * (k1.w + bf2f((unsigned short)ev[7]));
        }
    }
    float a0 = acch[0] * ATT_SCALE, a1 = acch[1] * ATT_SCALE;
    int h0 = hf * 2;
    alphaOut[(size_t)e * 4 + h0]     = a0;
    alphaOut[(size_t)e * 4 + h0 + 1] = a1;
    atomicMax(&mkeys[(size_t)d * 4 + h0],     fkey(a0));
    atomicMax(&mkeys[(size_t)d * 4 + h0 + 1], fkey(a1));
}

// ---------- exp pass ----------
__global__ void exp_pass(float* __restrict__ alpha,
                         const int* __restrict__ dstI,
                         const unsigned* __restrict__ mkeys,
                         float* __restrict__ ssum, int E) {
    int idx = blockIdx.x * blockDim.x + threadIdx.x;
    int total = E * 4;
    int stride = gridDim.x * blockDim.x;
    for (; idx < total; idx += stride) {
        int e = idx >> 2, h = idx & 3;
        int d = dstI[e];
        float m = fdecode(mkeys[(size_t)d * 4 + h]);
        float p = __expf(alpha[idx] - m);
        alpha[idx] = p;
        atomicAdd(&ssum[(size_t)d * 4 + h], p);
    }
}

// ---------- message scatter ----------
__global__ __launch_bounds__(256) void edge_msg(const unsigned short* __restrict__ EE,
                                                const int* __restrict__ srcI,
                                                const int* __restrict__ dstI,
                                                const float* __restrict__ Vm, int ldv,
                                                const float* __restrict__ P,
                                                const float* __restrict__ ssum,
                                                float* __restrict__ Out, int ldo, int E) {
    int gw = (int)((blockIdx.x * (size_t)blockDim.x + threadIdx.x) >> 6);
    int lane = threadIdx.x & 63;
    if (gw >= E) return;
    int d = dstI[gw], s = srcI[gw];
    int c = lane * 2;
    int h = c >> 5;
    float p = P[(size_t)gw * 4 + h];
    float a = p / (ssum[(size_t)d * 4 + h] + 1e-16f);
    unsigned eeb = *(const unsigned*)(EE + (size_t)gw * OUTF + c);
    float2 vv = *(const float2*)(Vm + (size_t)s * ldv + c);
    atomicAdd(&Out[(size_t)d * ldo + c],     (vv.x + bf2f((unsigned short)(eeb & 0xFFFFu))) * a);
    atomicAdd(&Out[(size_t)d * ldo + c + 1], (vv.y + bf2f((unsigned short)(eeb >> 16))) * a);
}

extern "C" void kernel_launch(void* const* d_in, const int* in_sizes, int n_in,
                              void* d_out, int out_size, void* d_ws, size_t ws_size,
                              hipStream_t stream) {
    const float* x    = (const float*)d_in[0];
    const int*   ei   = (const int*)d_in[1];
    const float* ea   = (const float*)d_in[2];
    const float* emb  = (const float*)d_in[3];
    const float* w1q  = (const float*)d_in[4];  const float* b1q = (const float*)d_in[5];
    const float* w1k  = (const float*)d_in[6];  const float* b1k = (const float*)d_in[7];
    const float* w1v  = (const float*)d_in[8];  const float* b1v = (const float*)d_in[9];
    const float* w1e  = (const float*)d_in[10];
    const float* w1s  = (const float*)d_in[11]; const float* b1s = (const float*)d_in[12];
    const float* w2q  = (const float*)d_in[13]; const float* b2q = (const float*)d_in[14];
    const float* w2k  = (const float*)d_in[15]; const float* b2k = (const float*)d_in[16];
    const float* w2v  = (const float*)d_in[17]; const float* b2v = (const float*)d_in[18];
    const float* w2e  = (const float*)d_in[19];
    const float* w2s  = (const float*)d_in[20]; const float* b2s = (const float*)d_in[21];

    const int* srcI = ei;
    const int* dstI = ei + NE;

    float* Y = (float*)d_ws;                              // N x 512: Q|K|V|H
    float* alpha = Y + (size_t)NN * 512;                  // E x 4
    unsigned* mkeys = (unsigned*)(alpha + (size_t)NE * 4);// N x 4
    float* ssum = (float*)(mkeys + (size_t)NN * 4);       // N x 4 (adjacent to mkeys: one memset)
    unsigned short* EE = (unsigned short*)(ssum + (size_t)NN * 4);  // E x 128 bf16
    unsigned short* WT1  = EE + (size_t)NE * OUTF;
    unsigned short* WT2  = WT1 + 512 * KPAD;
    unsigned short* WmT1 = WT2 + 512 * KPAD;
    unsigned short* WmT2 = WmT1 + OUTF * KPAD;
    float* T1    = (float*)(WmT2 + OUTF * KPAD);
    float* T2    = T1 + 4 * OUTF;
    float* bias1 = T2 + 4 * OUTF;
    float* bias2 = bias1 + 512;

    prep_kernel<<<128, 256, 0, stream>>>(w1q, w1k, w1v, w1s, w2q, w2k, w2v, w2s,
                                         w1e, w2e, emb,
                                         b1q, b1k, b1v, b1s, b2q, b2k, b2v, b2s,
                                         WT1, WT2, WmT1, WmT2, T1, T2, bias1, bias2);

    int ngrid = (NN + 127) / 128;   // 782
    int egrid = NE / 128;           // 5000

    // ---- layer 1 ----
    node_mfma<<<ngrid, 256, 0, stream>>>(x, K1, K1, 0, NN, WT1, bias1,
                                         Y + 0, Y + 128, Y + 256, Y + 384, 512, 512);
    hipMemsetAsync(mkeys, 0, (size_t)NN * 4 * 8, stream);
    edge_mfma<<<egrid, 256, 0, stream>>>(ea, srcI, dstI, WmT1, T1, Y + 0, Y + 128, 512,
                                         EE, alpha, mkeys);
    exp_pass<<<4096, 256, 0, stream>>>(alpha, dstI, mkeys, ssum, NE);
    edge_msg<<<NE / 4, 256, 0, stream>>>(EE, srcI, dstI, Y + 256, 512, alpha, ssum,
                                         Y + 384, 512, NE);

    // ---- layer 2 (relu on A load; S-block straight into d_out) ----
    node_mfma<<<ngrid, 256, 0, stream>>>(Y + 384, 512, OUTF, 1, NN, WT2, bias2,
                                         Y + 0, Y + 128, Y + 256, (float*)d_out, 512, 128);
    hipMemsetAsync(mkeys, 0, (size_t)NN * 4 * 8, stream);
    edge_mfma<<<egrid, 256, 0, stream>>>(ea, srcI, dstI, WmT2, T2, Y + 0, Y + 128, 512,
                                         EE, alpha, mkeys);
    exp_pass<<<4096, 256, 0, stream>>>(alpha, dstI, mkeys, ssum, NE);
    edge_msg<<<NE / 4, 256, 0, stream>>>(EE, srcI, dstI, Y + 256, 512, alpha, ssum,
                                         (float*)d_out, 128, NE);
}

// Round 3
// 1162.165 us; speedup vs baseline: 2.9281x; 2.2803x over previous
//
#include <hip/hip_runtime.h>

#define NN 100000
#define NE 640000
#define OUTF 128
#define K1 100
#define KE 118
#define KPAD 128
#define ASTR 136              // padded LDS row stride (ushorts)
#define ATT_SCALE 0.17677669529663687f
#define NTILE 5000            // NE/128
#define NSCANB 391            // ceil(NN/256)

typedef __attribute__((ext_vector_type(8))) short short8;
typedef __attribute__((ext_vector_type(4))) float f32x4;

__device__ __forceinline__ unsigned short f2bf(float f) {
    unsigned u = __float_as_uint(f);
    u += 0x7FFFu + ((u >> 16) & 1u);   // RNE
    return (unsigned short)(u >> 16);
}
__device__ __forceinline__ float bf2f(unsigned short h) {
    return __uint_as_float(((unsigned)h) << 16);
}

// ---------- prep: transposed bf16 weights [col][k]; WmT has one-hot T rows baked ----------
__global__ void prep_weights(
    const float* __restrict__ w1q, const float* __restrict__ w1k,
    const float* __restrict__ w1v, const float* __restrict__ w1s,
    const float* __restrict__ w2q, const float* __restrict__ w2k,
    const float* __restrict__ w2v, const float* __restrict__ w2s,
    const float* __restrict__ we1, const float* __restrict__ we2,
    const float* __restrict__ emb,
    const float* __restrict__ b1q, const float* __restrict__ b1k,
    const float* __restrict__ b1v, const float* __restrict__ b1s,
    const float* __restrict__ b2q, const float* __restrict__ b2k,
    const float* __restrict__ b2v, const float* __restrict__ b2s,
    unsigned short* __restrict__ WT1, unsigned short* __restrict__ WT2,
    unsigned short* __restrict__ WmT1, unsigned short* __restrict__ WmT2,
    float* __restrict__ bias1, float* __restrict__ bias2)
{
    int idx = blockIdx.x * blockDim.x + threadIdx.x;
    int stride = gridDim.x * blockDim.x;
    for (int i = idx; i < 512 * KPAD; i += stride) {
        int col = i >> 7, k = i & 127;
        int which = col >> 7, c = col & 127;
        const float* s1 = (which == 0) ? w1q : (which == 1) ? w1k : (which == 2) ? w1v : w1s;
        const float* s2 = (which == 0) ? w2q : (which == 1) ? w2k : (which == 2) ? w2v : w2s;
        float v1 = (k < K1) ? s1[k * OUTF + c] : 0.f;
        float v2 = s2[k * OUTF + c];
        WT1[i] = f2bf(v1); WT2[i] = f2bf(v2);
    }
    for (int i = idx; i < OUTF * KPAD; i += stride) {
        int col = i >> 7, k = i & 127;
        float v1 = 0.f, v2 = 0.f;
        if (k < 3)                 { v1 = we1[k * OUTF + col];       v2 = we2[k * OUTF + col]; }
        else if (k >= 4 && k < KE) { v1 = we1[(k - 1) * OUTF + col]; v2 = we2[(k - 1) * OUTF + col]; }
        else if (k >= KE && k < KE + 4) {
            int t = k - KE;
            #pragma unroll
            for (int r = 0; r < 8; r++) {
                float ev = emb[t * 8 + r];
                v1 += ev * we1[(117 + r) * OUTF + col];
                v2 += ev * we2[(117 + r) * OUTF + col];
            }
        }
        WmT1[i] = f2bf(v1); WmT2[i] = f2bf(v2);
    }
    for (int i = idx; i < 512; i += stride) {
        int which = i >> 7, c = i & 127;
        const float* sb1 = (which == 0) ? b1q : (which == 1) ? b1k : (which == 2) ? b1v : b1s;
        const float* sb2 = (which == 0) ? b2q : (which == 1) ? b2k : (which == 2) ? b2v : b2s;
        bias1[i] = sb1[c]; bias2[i] = sb2[c];
    }
}

// ---------- per-layer: EA fp32 -> EAp bf16 in MFMA-fragment order, one-hot etype; optional dst histogram ----------
__global__ __launch_bounds__(256) void prep_edges(const float* __restrict__ EA,
                                                  const int* __restrict__ dstI,
                                                  unsigned short* __restrict__ EAp,
                                                  int* __restrict__ cnt, int do_hist)
{
    __shared__ unsigned short Alds[128][ASTR];
    __shared__ int et_lds[128];
    int tid = threadIdx.x;
    int tile = blockIdx.x;
    int e0 = tile * 128;

    for (int idx = tid; idx < 128 * 64; idx += 256) {
        int r = idx >> 6, slot = idx & 63;
        int k = slot * 2;
        float2 v = make_float2(0.f, 0.f);
        if (k < KE) v = *(const float2*)(EA + (size_t)(e0 + r) * KE + k);
        if (slot == 1) { et_lds[r] = (int)v.y; v.y = 0.f; }  // col3 = etype -> zero
        unsigned pv = (unsigned)f2bf(v.x) | ((unsigned)f2bf(v.y) << 16);
        *(unsigned*)&Alds[r][k] = pv;
    }
    __syncthreads();
    if (tid < 128) {
        Alds[tid][KE + et_lds[tid]] = 0x3F80;   // bf16 1.0 one-hot
        if (do_hist) atomicAdd(&cnt[dstI[e0 + tid]], 1);
    }
    __syncthreads();
    // emit fragment-ordered: cid = ((g*4+ks)*16+l15)*4+l4, 16B each
    size_t base = (size_t)tile * 16384;
    #pragma unroll
    for (int it = 0; it < 8; it++) {
        int cid = it * 256 + tid;
        int g = cid >> 8, ks = (cid >> 6) & 3, l15 = (cid >> 2) & 15, l4 = cid & 3;
        uint4 v = *(const uint4*)&Alds[g * 16 + l15][ks * 32 + l4 * 8];
        *(uint4*)(EAp + base + (size_t)cid * 8) = v;
    }
}

// ---------- CSR build: scan + scatter ----------
__global__ void scan1(const int* __restrict__ cnt, int* __restrict__ S1, int* __restrict__ bsum) {
    __shared__ int sd[256];
    int t = blockIdx.x * 256 + threadIdx.x;
    sd[threadIdx.x] = (t < NN) ? cnt[t] : 0;
    __syncthreads();
    for (int off = 1; off < 256; off <<= 1) {
        int x = (threadIdx.x >= off) ? sd[threadIdx.x - off] : 0;
        __syncthreads();
        sd[threadIdx.x] += x;
        __syncthreads();
    }
    if (t < NN) S1[t] = sd[threadIdx.x];
    if (threadIdx.x == 255) bsum[blockIdx.x] = sd[255];
}
__global__ void scan2(const int* __restrict__ bsum, int* __restrict__ boff) {
    __shared__ int sd[512];
    int t = threadIdx.x;
    sd[t] = (t < NSCANB) ? bsum[t] : 0;
    __syncthreads();
    for (int off = 1; off < 512; off <<= 1) {
        int x = (t >= off) ? sd[t - off] : 0;
        __syncthreads();
        sd[t] += x;
        __syncthreads();
    }
    if (t < NSCANB) boff[t] = (t == 0) ? 0 : sd[t - 1];
}
__global__ void scan3(const int* __restrict__ S1, const int* __restrict__ boff,
                      const int* __restrict__ cnt,
                      int* __restrict__ row_start, int* __restrict__ cursor) {
    int t = blockIdx.x * 256 + threadIdx.x;
    if (t < NN) {
        int incl = S1[t] + boff[t >> 8];
        row_start[t + 1] = incl;
        cursor[t] = incl - cnt[t];
        if (t == 0) row_start[0] = 0;
    }
}
__global__ void scatter_csr(const int* __restrict__ srcI, const int* __restrict__ dstI,
                            int* __restrict__ cursor,
                            int* __restrict__ csr_src, int* __restrict__ csr_eid) {
    int e = blockIdx.x * 256 + threadIdx.x;
    if (e < NE) {
        int j = atomicAdd(&cursor[dstI[e]], 1);
        csr_src[j] = srcI[e];
        csr_eid[j] = e;
    }
}

// ---------- node GEMM (unchanged r2): Y = act(X)@Wcat + biascat, fp32 out ----------
__global__ __launch_bounds__(256) void node_mfma(
    const float* __restrict__ X, int ldx, int Kdim, int relu, int n,
    const unsigned short* __restrict__ WT, const float* __restrict__ bias,
    float* __restrict__ Y0, float* __restrict__ Y1,
    float* __restrict__ Y2, float* __restrict__ Y3,
    int ld012, int ld3)
{
    __shared__ unsigned short Alds[128][ASTR];
    int tid = threadIdx.x;
    int rowbase = blockIdx.x * 128;

    for (int idx = tid; idx < 128 * 68; idx += 256) {
        int r = idx / 68, kv = idx % 68;
        int k = kv * 2;
        float2 v = make_float2(0.f, 0.f);
        int gr = rowbase + r;
        if (gr < n && k < Kdim) v = *(const float2*)(X + (size_t)gr * ldx + k);
        if (relu) { v.x = fmaxf(v.x, 0.f); v.y = fmaxf(v.y, 0.f); }
        unsigned pv = (unsigned)f2bf(v.x) | ((unsigned)f2bf(v.y) << 16);
        *(unsigned*)&Alds[r][k] = pv;
    }
    __syncthreads();

    int lane = tid & 63, wid = tid >> 6;
    int wm = wid >> 1, wn = wid & 1;
    int l15 = lane & 15, l4 = lane >> 4;

    for (int nb = 0; nb < 4; nb++) {
        f32x4 acc[4][4];
        #pragma unroll
        for (int mf = 0; mf < 4; mf++)
            #pragma unroll
            for (int nf = 0; nf < 4; nf++)
                acc[mf][nf] = (f32x4){0.f, 0.f, 0.f, 0.f};

        const unsigned short* wbase = WT + (size_t)(nb * 128 + wn * 64 + l15) * KPAD + l4 * 8;
        #pragma unroll
        for (int ks = 0; ks < 4; ks++) {
            short8 af[4], bfr[4];
            #pragma unroll
            for (int mf = 0; mf < 4; mf++)
                af[mf] = *(const short8*)&Alds[wm * 64 + mf * 16 + l15][ks * 32 + l4 * 8];
            #pragma unroll
            for (int nf = 0; nf < 4; nf++)
                bfr[nf] = *(const short8*)(wbase + (size_t)nf * 16 * KPAD + ks * 32);
            #pragma unroll
            for (int mf = 0; mf < 4; mf++)
                #pragma unroll
                for (int nf = 0; nf < 4; nf++)
                    acc[mf][nf] = __builtin_amdgcn_mfma_f32_16x16x32_bf16(af[mf], bfr[nf], acc[mf][nf], 0, 0, 0);
        }

        float* Yb = (nb == 0) ? Y0 : (nb == 1) ? Y1 : (nb == 2) ? Y2 : Y3;
        int ld = (nb == 3) ? ld3 : ld012;
        #pragma unroll
        for (int nf = 0; nf < 4; nf++) {
            int col = wn * 64 + nf * 16 + l15;
            float bv = bias[nb * 128 + col];
            #pragma unroll
            for (int mf = 0; mf < 4; mf++) {
                #pragma unroll
                for (int rr = 0; rr < 4; rr++) {
                    int row = rowbase + wm * 64 + mf * 16 + l4 * 4 + rr;
                    if (row < n) Yb[(size_t)row * ld + col] = acc[mf][nf][rr] + bv;
                }
            }
        }
    }
}

// ---------- edge GEMM: fragment-direct A loads, EE bf16 written in-place over EAp ----------
__global__ __launch_bounds__(256) void edge_mfma(unsigned short* EAp,
                                                 const unsigned short* __restrict__ WmT)
{
    __shared__ unsigned short Slds[128][ASTR];
    int tid = threadIdx.x;
    int tile = blockIdx.x;
    int lane = tid & 63, wm = tid >> 6;
    int l15 = lane & 15, l4 = lane >> 4;
    size_t base = (size_t)tile * 16384;

    short8 af[2][4];
    #pragma unroll
    for (int mf = 0; mf < 2; mf++)
        #pragma unroll
        for (int ks = 0; ks < 4; ks++) {
            int g = wm * 2 + mf;
            int cid = ((g * 4 + ks) * 16 + l15) * 4 + l4;
            af[mf][ks] = *(const short8*)(EAp + base + (size_t)cid * 8);
        }

    f32x4 acc[2][8];
    #pragma unroll
    for (int mf = 0; mf < 2; mf++)
        #pragma unroll
        for (int nf = 0; nf < 8; nf++)
            acc[mf][nf] = (f32x4){0.f, 0.f, 0.f, 0.f};

    #pragma unroll
    for (int ks = 0; ks < 4; ks++) {
        short8 bfr[8];
        #pragma unroll
        for (int nf = 0; nf < 8; nf++)
            bfr[nf] = *(const short8*)(WmT + (size_t)(nf * 16 + l15) * KPAD + ks * 32 + l4 * 8);
        #pragma unroll
        for (int mf = 0; mf < 2; mf++)
            #pragma unroll
            for (int nf = 0; nf < 8; nf++)
                acc[mf][nf] = __builtin_amdgcn_mfma_f32_16x16x32_bf16(af[mf][ks], bfr[nf], acc[mf][nf], 0, 0, 0);
    }

    #pragma unroll
    for (int mf = 0; mf < 2; mf++)
        #pragma unroll
        for (int nf = 0; nf < 8; nf++)
            #pragma unroll
            for (int rr = 0; rr < 4; rr++)
                Slds[wm * 32 + mf * 16 + l4 * 4 + rr][nf * 16 + l15] = f2bf(acc[mf][nf][rr]);
    __syncthreads();

    #pragma unroll
    for (int it = 0; it < 8; it++) {
        int cid = it * 256 + tid;
        int row = cid >> 4, c8 = (cid & 15) * 8;
        uint4 v = *(const uint4*)&Slds[row][c8];
        *(uint4*)(EAp + base + (size_t)row * 128 + c8) = v;   // EE[e*128+c], linear
    }
}

// ---------- fused alpha + online softmax + aggregate + skip: one wave per dst node ----------
__global__ __launch_bounds__(256) void attn_node(
    const float* __restrict__ Y,                     // Q +0, K +128, V +256 (ld 512)
    const unsigned short* __restrict__ EE,
    const int* __restrict__ row_start,
    const int* __restrict__ csr_src, const int* __restrict__ csr_eid,
    const float* __restrict__ Hsrc, int ldh,
    float* __restrict__ Out, int ldo)
{
    int lane = threadIdx.x & 63;
    int gw = (int)((blockIdx.x * (size_t)blockDim.x + threadIdx.x) >> 6);
    int nW = (gridDim.x * blockDim.x) >> 6;
    int c2 = lane * 2;

    for (int d = gw; d < NN; d += nW) {
        int rs = row_start[d], re = row_start[d + 1];
        float2 q = *(const float2*)(Y + (size_t)d * 512 + c2);
        float m = -3.4e38f, s = 0.f, a0 = 0.f, a1 = 0.f;
        for (int j = rs; j < re; j++) {
            int sj = csr_src[j], ej = csr_eid[j];
            float2 kv = *(const float2*)(Y + (size_t)sj * 512 + 128 + c2);
            float2 vv = *(const float2*)(Y + (size_t)sj * 512 + 256 + c2);
            unsigned eeb = *(const unsigned*)(EE + (size_t)ej * 128 + c2);
            float e0 = bf2f((unsigned short)(eeb & 0xFFFFu));
            float e1 = bf2f((unsigned short)(eeb >> 16));
            float t = q.x * (kv.x + e0) + q.y * (kv.y + e1);
            t += __shfl_xor(t, 1); t += __shfl_xor(t, 2);
            t += __shfl_xor(t, 4); t += __shfl_xor(t, 8);
            float alpha = t * ATT_SCALE;
            float mn = fmaxf(m, alpha);
            float r = __expf(m - mn);
            float p = __expf(alpha - mn);
            s = s * r + p;
            a0 = a0 * r + p * (vv.x + e0);
            a1 = a1 * r + p * (vv.y + e1);
            m = mn;
        }
        float inv = 1.f / (s + 1e-16f);
        float2 h = *(const float2*)(Hsrc + (size_t)d * ldh + c2);
        float2 o;
        o.x = a0 * inv + h.x;
        o.y = a1 * inv + h.y;
        *(float2*)(Out + (size_t)d * ldo + c2) = o;
    }
}

extern "C" void kernel_launch(void* const* d_in, const int* in_sizes, int n_in,
                              void* d_out, int out_size, void* d_ws, size_t ws_size,
                              hipStream_t stream) {
    const float* x    = (const float*)d_in[0];
    const int*   ei   = (const int*)d_in[1];
    const float* ea   = (const float*)d_in[2];
    const float* emb  = (const float*)d_in[3];
    const float* w1q  = (const float*)d_in[4];  const float* b1q = (const float*)d_in[5];
    const float* w1k  = (const float*)d_in[6];  const float* b1k = (const float*)d_in[7];
    const float* w1v  = (const float*)d_in[8];  const float* b1v = (const float*)d_in[9];
    const float* w1e  = (const float*)d_in[10];
    const float* w1s  = (const float*)d_in[11]; const float* b1s = (const float*)d_in[12];
    const float* w2q  = (const float*)d_in[13]; const float* b2q = (const float*)d_in[14];
    const float* w2k  = (const float*)d_in[15]; const float* b2k = (const float*)d_in[16];
    const float* w2v  = (const float*)d_in[17]; const float* b2v = (const float*)d_in[18];
    const float* w2e  = (const float*)d_in[19];
    const float* w2s  = (const float*)d_in[20]; const float* b2s = (const float*)d_in[21];

    const int* srcI = ei;
    const int* dstI = ei + NE;

    float* Y = (float*)d_ws;                                   // N x 512 fp32: Q|K|V|H
    unsigned short* EAp = (unsigned short*)(Y + (size_t)NN * 512);  // E x 128 bf16 (becomes EE)
    int* csr_src   = (int*)(EAp + (size_t)NE * 128);
    int* csr_eid   = csr_src + NE;
    int* row_start = csr_eid + NE;            // N+1
    int* cursor    = row_start + NN + 1;
    int* cnt       = cursor + NN;
    int* S1        = cnt + NN;
    int* bsum      = S1 + NN;
    int* boff      = bsum + NSCANB;
    unsigned short* WT1  = (unsigned short*)(boff + NSCANB + 1);
    unsigned short* WT2  = WT1 + 512 * KPAD;
    unsigned short* WmT1 = WT2 + 512 * KPAD;
    unsigned short* WmT2 = WmT1 + OUTF * KPAD;
    float* bias1 = (float*)(WmT2 + OUTF * KPAD);
    float* bias2 = bias1 + 512;

    prep_weights<<<128, 256, 0, stream>>>(w1q, w1k, w1v, w1s, w2q, w2k, w2v, w2s,
                                          w1e, w2e, emb,
                                          b1q, b1k, b1v, b1s, b2q, b2k, b2v, b2s,
                                          WT1, WT2, WmT1, WmT2, bias1, bias2);
    hipMemsetAsync(cnt, 0, (size_t)NN * sizeof(int), stream);
    prep_edges<<<NTILE, 256, 0, stream>>>(ea, dstI, EAp, cnt, 1);
    scan1<<<NSCANB, 256, 0, stream>>>(cnt, S1, bsum);
    scan2<<<1, 512, 0, stream>>>(bsum, boff);
    scan3<<<NSCANB, 256, 0, stream>>>(S1, boff, cnt, row_start, cursor);
    scatter_csr<<<NE / 256, 256, 0, stream>>>(srcI, dstI, cursor, csr_src, csr_eid);

    int ngrid = (NN + 127) / 128;

    // ---- layer 1 ----
    node_mfma<<<ngrid, 256, 0, stream>>>(x, K1, K1, 0, NN, WT1, bias1,
                                         Y + 0, Y + 128, Y + 256, Y + 384, 512, 512);
    edge_mfma<<<NTILE, 256, 0, stream>>>(EAp, WmT1);
    attn_node<<<2048, 256, 0, stream>>>(Y, EAp, row_start, csr_src, csr_eid,
                                        Y + 384, 512, Y + 384, 512);

    // ---- layer 2 ----
    node_mfma<<<ngrid, 256, 0, stream>>>(Y + 384, 512, OUTF, 1, NN, WT2, bias2,
                                         Y + 0, Y + 128, Y + 256, (float*)d_out, 512, 128);
    prep_edges<<<NTILE, 256, 0, stream>>>(ea, dstI, EAp, cnt, 0);   // rebuild EAp (EE1 overwrote it)
    edge_mfma<<<NTILE, 256, 0, stream>>>(EAp, WmT2);
    attn_node<<<2048, 256, 0, stream>>>(Y, EAp, row_start, csr_src, csr_eid,
                                        (float*)d_out, 128, (float*)d_out, 128);
}